// Round 5
// baseline (331.029 us; speedup 1.0000x reference)
//
#include <hip/hip_runtime.h>
#include <math.h>

// Problem constants (from reference setup_inputs)
#define NB     64      // batch
#define N1V    8192    // obj points per batch
#define NV     778     // recon / gt verts
#define NVP    780     // padded to multiple of 4
#define NFACE  1538
#define NZ     64
#define NPAR   61
#define NPRIOR 204
#define PPT    4       // obj points per thread in main role
#define MAIN_BLOCKS (NB * 8)                 // 512: 1024 obj pts per block
#define CHAM_BLOCKS (NB * 4)                 // 256: (batch, dir, half)
#define TOT_BLOCKS  (MAIN_BLOCKS + CHAM_BLOCKS)
#define HALF_SRC 389                          // 778/2 sources per chamfer block
#define BIAS   0.0625f // makes rec/pri partial distance non-negative (2ab <= 0.06)

// ws float4 layout per batch (BATCH_F4 float4s, 64B-aligned stride):
//   [0,780)     gt4   (x,y,z,|t|^2), pads w=1e30
//   [780,1560)  rec4  (x,y,z,|t|^2+BIAS), pads w=1e30
//   [1560,1764) pri4  (biased, subset of rec4)
//   [1764,2542) nrm4  (nx,ny,nz,0)
#define BATCH_F4 2544                  // padded: 2544*16B = 64B multiple
#define PART_OFF (NB * BATCH_F4 * 4)   // float offset of partials[TOT_BLOCKS][8]

// Constant-address-space scalar view: uniform loads -> s_load (SMEM), no LDS,
// no vmcnt in the hot loops. Scalar float avoids the HIP_vector_type ctor
// address-space binding problem.
typedef const __attribute__((address_space(4))) float cfloat;
__device__ __forceinline__ cfloat* cpc(const float* p) {
    return (cfloat*)(unsigned long long)p;
}

__device__ __constant__ int c_prior[NPRIOR] = {
  697,698,699,700,712,713,714,715,737,738,739,740,741,743,744,745,746,748,749,750,
  753,754,755,756,757,758,759,760,761,762,763,764,765,766,767,768,
  46,47,48,49,164,165,166,167,194,195,223,237,238,280,281,298,301,317,320,323,
  324,325,326,327,328,329,330,331,332,333,340,341,342,343,344,345,346,347,348,349,
  350,351,352,353,354,355,
  356,357,358,359,375,376,386,387,396,397,402,403,413,429,433,434,435,436,437,438,
  439,440,441,442,443,444,452,453,454,455,456,459,460,461,462,463,464,465,466,467,
  468,469,470,471,484,485,486,496,497,506,507,513,514,524,545,546,547,548,549,550,
  551,552,553,555,563,564,565,566,567,570,572,573,574,575,576,577,578,
  580,581,582,583,600,601,602,614,615,624,625,630,631,641,663,664,665,666,667,668,
  670,672,680,681,682,683,684,686,687,688,689,690,691,692,693,694,695,
  73,96,98,99,772,774,775,777
};

// ---------------- Kernel 0: per-batch target arrays + normals ----------------
__global__ __launch_bounds__(256) void k_prep(const float* __restrict__ recon,
                                              const float* __restrict__ gt,
                                              const int* __restrict__ faces,
                                              float4* __restrict__ ws4) {
    int b = blockIdx.x, tid = threadIdx.x;
    __shared__ float4 s_r[NV];
    __shared__ float s_vnx[NV], s_vny[NV], s_vnz[NV];
    const float* rb = recon + (size_t)b * NV * 3;
    const float* gb = gt    + (size_t)b * NV * 3;
    float4* gt4  = ws4 + (size_t)b * BATCH_F4;
    float4* rec4 = gt4 + NVP;
    float4* pri4 = rec4 + NVP;
    float4* nrm4 = pri4 + NPRIOR;
    for (int j = tid; j < NVP; j += 256) {
        if (j < NV) {
            float x = rb[3*j], y = rb[3*j+1], z = rb[3*j+2];
            float4 r = make_float4(x, y, z, x*x + y*y + z*z + BIAS);
            s_r[j] = r; rec4[j] = r;
            x = gb[3*j]; y = gb[3*j+1]; z = gb[3*j+2];
            gt4[j] = make_float4(x, y, z, x*x + y*y + z*z);
            s_vnx[j] = 0.0f; s_vny[j] = 0.0f; s_vnz[j] = 0.0f;
        } else {
            float4 pad = make_float4(0.f, 0.f, 0.f, 1e30f);
            rec4[j] = pad; gt4[j] = pad;
        }
    }
    __syncthreads();
    for (int f = tid; f < NFACE; f += 256) {
        int i0 = faces[3*f], i1 = faces[3*f+1], i2 = faces[3*f+2];
        float4 p0 = s_r[i0], p1 = s_r[i1], p2 = s_r[i2];
        float e1x = p1.x - p0.x, e1y = p1.y - p0.y, e1z = p1.z - p0.z;
        float e2x = p2.x - p0.x, e2y = p2.y - p0.y, e2z = p2.z - p0.z;
        float fx = e1y * e2z - e1z * e2y;
        float fy = e1z * e2x - e1x * e2z;
        float fz = e1x * e2y - e1y * e2x;
        atomicAdd(&s_vnx[i0], fx); atomicAdd(&s_vny[i0], fy); atomicAdd(&s_vnz[i0], fz);
        atomicAdd(&s_vnx[i1], fx); atomicAdd(&s_vny[i1], fy); atomicAdd(&s_vnz[i1], fz);
        atomicAdd(&s_vnx[i2], fx); atomicAdd(&s_vny[i2], fy); atomicAdd(&s_vnz[i2], fz);
    }
    __syncthreads();
    for (int j = tid; j < NV; j += 256) {
        float x = s_vnx[j], y = s_vny[j], z = s_vnz[j];
        float inv = 1.0f / (sqrtf(x*x + y*y + z*z) + 1e-12f);
        nrm4[j] = make_float4(x * inv, y * inv, z * inv, 0.0f);
    }
    for (int k = tid; k < NPRIOR; k += 256) pri4[k] = s_r[c_prior[k]];
}

// Distance macro on scalar constant-AS loads: 4 targets per step.
#define LOAD16(T, o) \
    float T##0x = T[(o)],    T##0y = T[(o)+1],  T##0z = T[(o)+2],  T##0w = T[(o)+3];  \
    float T##1x = T[(o)+4],  T##1y = T[(o)+5],  T##1z = T[(o)+6],  T##1w = T[(o)+7];  \
    float T##2x = T[(o)+8],  T##2y = T[(o)+9],  T##2z = T[(o)+10], T##2w = T[(o)+11]; \
    float T##3x = T[(o)+12], T##3y = T[(o)+13], T##3z = T[(o)+14], T##3w = T[(o)+15];

// ---------------- Fused kernel: main KNNs (0..511) + chamfer (512..767) ------
__global__ __launch_bounds__(256) void k_fused(const float* __restrict__ obj,
                                               const float4* __restrict__ ws4,
                                               float* __restrict__ part) {
    __shared__ float s_red[5];
    int tid = threadIdx.x;

    if (blockIdx.x >= MAIN_BLOCKS) {
        // ================== CHAMFER ROLE ==================
        int c    = blockIdx.x - MAIN_BLOCKS;
        int b    = c >> 2;
        int dir  = (c >> 1) & 1;   // 0: rec->gt, 1: gt->rec
        int half = c & 1;
        if (tid == 0) s_red[0] = 0.0f;
        __syncthreads();
        const float4* base = ws4 + (size_t)b * BATCH_F4;
        const float4* srcv = dir ? base : (base + NVP);           // gt4 : rec4
        cfloat* tgt = cpc((const float*)(dir ? (base + NVP) : base)); // rec4 : gt4

        const int CPT = 2;               // 256*2 = 512 >= 389 sources
        float nax[CPT], nay[CPT], naz[CPT], a2[CPT], m[CPT];
        bool valid[CPT];
#pragma unroll
        for (int k = 0; k < CPT; ++k) {
            int p = half * HALF_SRC + tid + 256 * k;
            valid[k] = (p < (half + 1) * HALF_SRC);
            float4 s = srcv[valid[k] ? p : 0];
            nax[k] = -2.0f * s.x; nay[k] = -2.0f * s.y; naz[k] = -2.0f * s.z;
            a2[k] = s.w;                  // includes +BIAS when src=rec (dir 0)
            m[k] = 3.4e38f;
        }
        for (int j = 0; j < NVP * 4; j += 16) {
            LOAD16(tgt, j)
#pragma unroll
            for (int k = 0; k < CPT; ++k) {
                float d0 = fmaf(nax[k], tgt0x, fmaf(nay[k], tgt0y, fmaf(naz[k], tgt0z, tgt0w)));
                float d1 = fmaf(nax[k], tgt1x, fmaf(nay[k], tgt1y, fmaf(naz[k], tgt1z, tgt1w)));
                float d2 = fmaf(nax[k], tgt2x, fmaf(nay[k], tgt2y, fmaf(naz[k], tgt2z, tgt2w)));
                float d3 = fmaf(nax[k], tgt3x, fmaf(nay[k], tgt3y, fmaf(naz[k], tgt3z, tgt3w)));
                m[k] = fminf(fminf(m[k], d0), d1);
                m[k] = fminf(fminf(m[k], d2), d3);
            }
        }
        // exactly one of {src,tgt} carries +BIAS in w for either dir -> -BIAS
        float local = 0.0f;
#pragma unroll
        for (int k = 0; k < CPT; ++k)
            if (valid[k]) local += fmaxf(a2[k] + m[k] - BIAS, 0.0f);
        atomicAdd(&s_red[0], local);
        __syncthreads();
        if (tid < 8) {
            float v = (tid == 2) ? s_red[0] : 0.0f;
            part[(size_t)blockIdx.x * 8 + tid] = v;
        }
        return;
    }

    // ================== MAIN ROLE ==================
    int b = blockIdx.x >> 3;     // batch
    int chunk = blockIdx.x & 7;  // 1024-point chunk
    if (tid < 5) s_red[tid] = 0.0f;
    __syncthreads();

    const float4* base = ws4 + (size_t)b * BATCH_F4;
    cfloat* tg = cpc((const float*)base);             // gt4
    cfloat* tr = cpc((const float*)(base + NVP));     // rec4 (biased)
    cfloat* tp = cpc((const float*)(base + 2 * NVP)); // pri4 (biased)
    const float4* rec4v = base + NVP;                 // divergent epilogue gathers
    const float4* nrm4v = base + 2 * NVP + NPRIOR;

    // each thread: PPT=4 consecutive obj points (12 floats = 3 float4)
    const float* ob = obj + ((size_t)b * N1V + (size_t)chunk * 1024) * 3;
    const float4* ob4 = (const float4*)(ob + (size_t)tid * PPT * 3);
    float4 q0 = ob4[0], q1 = ob4[1], q2 = ob4[2];
    float px[PPT], py[PPT], pz[PPT];
    px[0]=q0.x; py[0]=q0.y; pz[0]=q0.z;
    px[1]=q0.w; py[1]=q1.x; pz[1]=q1.y;
    px[2]=q1.z; py[2]=q1.w; pz[2]=q2.x;
    px[3]=q2.y; py[3]=q2.z; pz[3]=q2.w;

    float nax[PPT], nay[PPT], naz[PPT], a2[PPT];
    float mgt[PPT], mpri[PPT];
    unsigned int mu[PPT];
#pragma unroll
    for (int i = 0; i < PPT; ++i) {
        nax[i] = -2.0f * px[i]; nay[i] = -2.0f * py[i]; naz[i] = -2.0f * pz[i];
        a2[i] = px[i]*px[i] + py[i]*py[i] + pz[i]*pz[i];
        mgt[i] = 3.4e38f; mpri[i] = 3.4e38f; mu[i] = 0xFFFFFFFFu;
    }

    // --- gt loop: scalar target stream, 4 targets/iter ---
    for (int j = 0; j < NVP * 4; j += 16) {
        LOAD16(tg, j)
#pragma unroll
        for (int i = 0; i < PPT; ++i) {
            float d0 = fmaf(nax[i], tg0x, fmaf(nay[i], tg0y, fmaf(naz[i], tg0z, tg0w)));
            float d1 = fmaf(nax[i], tg1x, fmaf(nay[i], tg1y, fmaf(naz[i], tg1z, tg1w)));
            float d2 = fmaf(nax[i], tg2x, fmaf(nay[i], tg2y, fmaf(naz[i], tg2z, tg2w)));
            float d3 = fmaf(nax[i], tg3x, fmaf(nay[i], tg3y, fmaf(naz[i], tg3z, tg3w)));
            mgt[i] = fminf(fminf(mgt[i], d0), d1);
            mgt[i] = fminf(fminf(mgt[i], d2), d3);
        }
    }
    // --- rec loop: packed (distance | index) uint-min argmin ---
    // biased d >= 0, so float bits are monotone as uint; low 10 bits carry j.
    for (int j4 = 0; j4 < NVP; j4 += 4) {
        int j = j4 * 4;
        LOAD16(tr, j)
#pragma unroll
        for (int i = 0; i < PPT; ++i) {
            float d0 = fmaf(nax[i], tr0x, fmaf(nay[i], tr0y, fmaf(naz[i], tr0z, tr0w)));
            float d1 = fmaf(nax[i], tr1x, fmaf(nay[i], tr1y, fmaf(naz[i], tr1z, tr1w)));
            float d2 = fmaf(nax[i], tr2x, fmaf(nay[i], tr2y, fmaf(naz[i], tr2z, tr2w)));
            float d3 = fmaf(nax[i], tr3x, fmaf(nay[i], tr3y, fmaf(naz[i], tr3z, tr3w)));
            unsigned int u0 = (__float_as_uint(d0) & 0xFFFFFC00u) | (unsigned)(j4);
            unsigned int u1 = (__float_as_uint(d1) & 0xFFFFFC00u) | (unsigned)(j4+1);
            unsigned int u2 = (__float_as_uint(d2) & 0xFFFFFC00u) | (unsigned)(j4+2);
            unsigned int u3 = (__float_as_uint(d3) & 0xFFFFFC00u) | (unsigned)(j4+3);
            mu[i] = min(mu[i], min(min(u0, u1), min(u2, u3)));
        }
    }
    // --- prior loop: biased values ---
    for (int j = 0; j < NPRIOR * 4; j += 16) {
        LOAD16(tp, j)
#pragma unroll
        for (int i = 0; i < PPT; ++i) {
            float d0 = fmaf(nax[i], tp0x, fmaf(nay[i], tp0y, fmaf(naz[i], tp0z, tp0w)));
            float d1 = fmaf(nax[i], tp1x, fmaf(nay[i], tp1y, fmaf(naz[i], tp1z, tp1w)));
            float d2 = fmaf(nax[i], tp2x, fmaf(nay[i], tp2y, fmaf(naz[i], tp2z, tp2w)));
            float d3 = fmaf(nax[i], tp3x, fmaf(nay[i], tp3y, fmaf(naz[i], tp3z, tp3w)));
            mpri[i] = fminf(fminf(mpri[i], d0), d1);
            mpri[i] = fminf(fminf(mpri[i], d2), d3);
        }
    }

    float lS_cmap = 0.0f, lN_cmap = 0.0f, lN_gt = 0.0f, lN_cons = 0.0f, lS_pen = 0.0f;
#pragma unroll
    for (int i = 0; i < PPT; ++i) {
        float dgt  = fmaxf(a2[i] + mgt[i],           0.0f);
        float dpri = fmaxf(a2[i] + (mpri[i] - BIAS), 0.0f);
        int j = (int)(mu[i] & 0x3FFu);
        float4 t  = rec4v[j];
        float4 nr = nrm4v[j];
        // exact d_rec recompute for the chosen neighbor
        float dot = fmaf(nax[i], t.x, fmaf(nay[i], t.y, fmaf(naz[i], t.z, t.w - BIAS)));
        float drec = fmaxf(a2[i] + dot, 0.0f);
        bool cm = drec < 1e-4f;                 // d_rec < 0.01^2
        bool rc = sqrtf(drec) < 0.005f;         // recon_cmap
        bool gc = sqrtf(dgt)  < 0.005f;         // gt_cmap
        if (cm) { lS_cmap += dpri; lN_cmap += 1.0f; }
        if (gc) { lN_gt += 1.0f; if (rc) lN_cons += 1.0f; }
        float ddot = (t.x - px[i]) * nr.x
                   + (t.y - py[i]) * nr.y
                   + (t.z - pz[i]) * nr.z;
        if (ddot > 0.0f) lS_pen += drec;
    }
    atomicAdd(&s_red[0], lS_cmap);
    atomicAdd(&s_red[1], lN_cmap);
    atomicAdd(&s_red[2], lN_gt);
    atomicAdd(&s_red[3], lN_cons);
    atomicAdd(&s_red[4], lS_pen);
    __syncthreads();
    if (tid < 8) {
        float v = (tid >= 3) ? s_red[tid - 3] : 0.0f;
        part[(size_t)blockIdx.x * 8 + tid] = v;
    }
}

// ---------------- Finalize: param/KLD reductions + partial row-sum + loss ----
__global__ __launch_bounds__(256) void k_final(const float* __restrict__ part,
                                               const float* __restrict__ mean,
                                               const float* __restrict__ log_var,
                                               const float* __restrict__ rp,
                                               const float* __restrict__ xp,
                                               float* __restrict__ out) {
    int tid = threadIdx.x;
    __shared__ float red[8];
    if (tid < 8) red[tid] = 0.0f;
    __syncthreads();
    float l2=0, l3=0, l4=0, l5=0, l6=0, l7=0;
    for (int r = tid; r < TOT_BLOCKS; r += 256) {
        const float* row = part + (size_t)r * 8;
        l2 += row[2]; l3 += row[3]; l4 += row[4];
        l5 += row[5]; l6 += row[6]; l7 += row[7];
    }
    float s_param = 0.0f, s_kld = 0.0f;
    for (int i = tid; i < NB * NPAR; i += 256) {
        float d = rp[i] - xp[i];
        s_param += d * d;
    }
    for (int i = tid; i < NB * NZ; i += 256) {
        float m = mean[i], lv = log_var[i];
        s_kld += 1.0f + lv - m * m - expf(lv);
    }
    atomicAdd(&red[0], s_param);
    atomicAdd(&red[1], s_kld);
    atomicAdd(&red[2], l2);
    atomicAdd(&red[3], l3);
    atomicAdd(&red[4], l4);
    atomicAdd(&red[5], l5);
    atomicAdd(&red[6], l6);
    atomicAdd(&red[7], l7);
    __syncthreads();
    if (tid == 0) {
        const float fB = 64.0f;
        float param_loss  = red[0] / fB;
        float KLD         = -0.5f * red[1] / fB * 10.0f;
        float recon_loss  = red[2] / fB;
        float cmap_loss   = 3000.0f * red[3] / (fB * red[4]);
        float consistency = -5.0f * red[6] / (red[5] + 0.0001f);
        float penetr      = 100.0f * red[7] / fB;
        out[0] = (recon_loss + KLD) + 0.1f * param_loss + 1000.0f * cmap_loss
               + 10.0f * consistency + 10.0f * penetr;
    }
}

extern "C" void kernel_launch(void* const* d_in, const int* in_sizes, int n_in,
                              void* d_out, int out_size, void* d_ws, size_t ws_size,
                              hipStream_t stream) {
    (void)in_sizes; (void)n_in; (void)out_size; (void)ws_size;
    const float* obj     = (const float*)d_in[0];
    const float* recon   = (const float*)d_in[1];
    const float* gt      = (const float*)d_in[2];
    const float* mean    = (const float*)d_in[3];
    const float* log_var = (const float*)d_in[4];
    const float* rp      = (const float*)d_in[5];
    const float* xp      = (const float*)d_in[6];
    const int*   faces   = (const int*)d_in[7];
    float4* ws4 = (float4*)d_ws;
    float* part = (float*)d_ws + PART_OFF;
    float* out  = (float*)d_out;

    k_prep <<<NB,         256, 0, stream>>>(recon, gt, faces, ws4);
    k_fused<<<TOT_BLOCKS, 256, 0, stream>>>(obj, ws4, part);
    k_final<<<1,          256, 0, stream>>>(part, mean, log_var, rp, xp, out);
}

// Round 6
// 212.569 us; speedup vs baseline: 1.5573x; 1.5573x over previous
//
#include <hip/hip_runtime.h>
#include <math.h>

// Problem constants (from reference setup_inputs)
#define NB     64      // batch
#define N1V    8192    // obj points per batch
#define NV     778     // recon / gt verts
#define NVP    780     // padded to multiple of 4
#define NFACE  1538
#define NZ     64
#define NPAR   61
#define NPRIOR 204
#define PPT    4       // obj points per thread
#define BIAS   0.0625f // makes rec/pri partial distance non-negative (2ab <= 0.06)

// role block ranges in k_fused
#define REC_BLOCKS 512                       // (batch, chunk-of-1024): rec + prior streams
#define GT_BLOCKS  512                       // (batch, chunk-of-1024): gt stream
#define CH_BLOCKS  256                       // (batch, dir, half): chamfer
#define NROLE_BLOCKS (REC_BLOCKS + GT_BLOCKS + CH_BLOCKS)   // 1280
#define CMB_BLOCKS 512
#define TOT_ROWS   (NROLE_BLOCKS + CMB_BLOCKS)              // 1792
#define HALF_SRC   389

// ws float4 layout per batch (BATCH_F4 float4s):
//   [0,780)     gt4   (x,y,z,|t|^2), pads w=1e30
//   [780,1560)  rec4  (x,y,z,|t|^2+BIAS), pads w=1e30
//   [1560,1764) pri4  (biased, subset of rec4)
//   [1764,2542) nrm4  (nx,ny,nz,0)
#define BATCH_F4 2544
// float offsets in ws
#define PART_OFF (NB * BATCH_F4 * 4)          // partials[TOT_ROWS][8]
#define DREC_OFF (PART_OFF + TOT_ROWS * 8)    // drec[NB*N1V]
#define GC_OFF   (DREC_OFF + NB * N1V)        // gc bytes [NB*N1V] (as uints)

__device__ __constant__ int c_prior[NPRIOR] = {
  697,698,699,700,712,713,714,715,737,738,739,740,741,743,744,745,746,748,749,750,
  753,754,755,756,757,758,759,760,761,762,763,764,765,766,767,768,
  46,47,48,49,164,165,166,167,194,195,223,237,238,280,281,298,301,317,320,323,
  324,325,326,327,328,329,330,331,332,333,340,341,342,343,344,345,346,347,348,349,
  350,351,352,353,354,355,
  356,357,358,359,375,376,386,387,396,397,402,403,413,429,433,434,435,436,437,438,
  439,440,441,442,443,444,452,453,454,455,456,459,460,461,462,463,464,465,466,467,
  468,469,470,471,484,485,486,496,497,506,507,513,514,524,545,546,547,548,549,550,
  551,552,553,555,563,564,565,566,567,570,572,573,574,575,576,577,578,
  580,581,582,583,600,601,602,614,615,624,625,630,631,641,663,664,665,666,667,668,
  670,672,680,681,682,683,684,686,687,688,689,690,691,692,693,694,695,
  73,96,98,99,772,774,775,777
};

// ---------------- Kernel 0: per-batch target arrays + normals ----------------
__global__ __launch_bounds__(256) void k_prep(const float* __restrict__ recon,
                                              const float* __restrict__ gt,
                                              const int* __restrict__ faces,
                                              float4* __restrict__ ws4) {
    int b = blockIdx.x, tid = threadIdx.x;
    __shared__ float4 s_r[NV];
    __shared__ float s_vnx[NV], s_vny[NV], s_vnz[NV];
    const float* rb = recon + (size_t)b * NV * 3;
    const float* gb = gt    + (size_t)b * NV * 3;
    float4* gt4  = ws4 + (size_t)b * BATCH_F4;
    float4* rec4 = gt4 + NVP;
    float4* pri4 = rec4 + NVP;
    float4* nrm4 = pri4 + NPRIOR;
    for (int j = tid; j < NVP; j += 256) {
        if (j < NV) {
            float x = rb[3*j], y = rb[3*j+1], z = rb[3*j+2];
            float4 r = make_float4(x, y, z, x*x + y*y + z*z + BIAS);
            s_r[j] = r; rec4[j] = r;
            x = gb[3*j]; y = gb[3*j+1]; z = gb[3*j+2];
            gt4[j] = make_float4(x, y, z, x*x + y*y + z*z);
            s_vnx[j] = 0.0f; s_vny[j] = 0.0f; s_vnz[j] = 0.0f;
        } else {
            float4 pad = make_float4(0.f, 0.f, 0.f, 1e30f);
            rec4[j] = pad; gt4[j] = pad;
        }
    }
    __syncthreads();
    for (int f = tid; f < NFACE; f += 256) {
        int i0 = faces[3*f], i1 = faces[3*f+1], i2 = faces[3*f+2];
        float4 p0 = s_r[i0], p1 = s_r[i1], p2 = s_r[i2];
        float e1x = p1.x - p0.x, e1y = p1.y - p0.y, e1z = p1.z - p0.z;
        float e2x = p2.x - p0.x, e2y = p2.y - p0.y, e2z = p2.z - p0.z;
        float fx = e1y * e2z - e1z * e2y;
        float fy = e1z * e2x - e1x * e2z;
        float fz = e1x * e2y - e1y * e2x;
        atomicAdd(&s_vnx[i0], fx); atomicAdd(&s_vny[i0], fy); atomicAdd(&s_vnz[i0], fz);
        atomicAdd(&s_vnx[i1], fx); atomicAdd(&s_vny[i1], fy); atomicAdd(&s_vnz[i1], fz);
        atomicAdd(&s_vnx[i2], fx); atomicAdd(&s_vny[i2], fy); atomicAdd(&s_vnz[i2], fz);
    }
    __syncthreads();
    for (int j = tid; j < NV; j += 256) {
        float x = s_vnx[j], y = s_vny[j], z = s_vnz[j];
        float inv = 1.0f / (sqrtf(x*x + y*y + z*z) + 1e-12f);
        nrm4[j] = make_float4(x * inv, y * inv, z * inv, 0.0f);
    }
    for (int k = tid; k < NPRIOR; k += 256) pri4[k] = s_r[c_prior[k]];
}

// ---------------- Fused role kernel ----------------
// blocks [0,512): rec+prior KNN   [512,1024): gt KNN   [1024,1280): chamfer
__global__ __launch_bounds__(256) void k_fused(const float* __restrict__ obj,
                                               const float4* __restrict__ ws4,
                                               float* __restrict__ part,
                                               float* __restrict__ drec_arr,
                                               unsigned int* __restrict__ gc_arr) {
    __shared__ float4 s_t[NVP];
    __shared__ float4 s_p[NPRIOR];
    __shared__ float s_red[4];
    int tid = threadIdx.x;
    int blk = blockIdx.x;

    if (blk < REC_BLOCKS) {
        // ============ REC + PRIOR ROLE ============
        int b = blk >> 3, chunk = blk & 7;
        const float4* base = ws4 + (size_t)b * BATCH_F4;
        const float4* rec4v = base + NVP;
        const float4* pri4v = base + 2 * NVP;
        const float4* nrm4v = pri4v + NPRIOR;
        for (int j = tid; j < NVP; j += 256) s_t[j] = rec4v[j];
        for (int k = tid; k < NPRIOR; k += 256) s_p[k] = pri4v[k];
        if (tid < 4) s_red[tid] = 0.0f;
        __syncthreads();

        const float* ob = obj + ((size_t)b * N1V + (size_t)chunk * 1024) * 3;
        const float4* ob4 = (const float4*)(ob + (size_t)tid * PPT * 3);
        float4 q0 = ob4[0], q1 = ob4[1], q2 = ob4[2];
        float px[PPT], py[PPT], pz[PPT];
        px[0]=q0.x; py[0]=q0.y; pz[0]=q0.z;
        px[1]=q0.w; py[1]=q1.x; pz[1]=q1.y;
        px[2]=q1.z; py[2]=q1.w; pz[2]=q2.x;
        px[3]=q2.y; py[3]=q2.z; pz[3]=q2.w;

        float nax[PPT], nay[PPT], naz[PPT], a2[PPT], mpri[PPT];
        unsigned int mu[PPT];
#pragma unroll
        for (int i = 0; i < PPT; ++i) {
            nax[i] = -2.0f * px[i]; nay[i] = -2.0f * py[i]; naz[i] = -2.0f * pz[i];
            a2[i] = px[i]*px[i] + py[i]*py[i] + pz[i]*pz[i];
            mpri[i] = 3.4e38f; mu[i] = 0xFFFFFFFFu;
        }
        // rec stream: packed (distance|index) uint-min argmin (biased d >= 0)
        for (int j = 0; j < NVP; j += 4) {
            float4 t0 = s_t[j], t1 = s_t[j+1], t2 = s_t[j+2], t3 = s_t[j+3];
#pragma unroll
            for (int i = 0; i < PPT; ++i) {
                float d0 = fmaf(nax[i], t0.x, fmaf(nay[i], t0.y, fmaf(naz[i], t0.z, t0.w)));
                float d1 = fmaf(nax[i], t1.x, fmaf(nay[i], t1.y, fmaf(naz[i], t1.z, t1.w)));
                float d2 = fmaf(nax[i], t2.x, fmaf(nay[i], t2.y, fmaf(naz[i], t2.z, t2.w)));
                float d3 = fmaf(nax[i], t3.x, fmaf(nay[i], t3.y, fmaf(naz[i], t3.z, t3.w)));
                unsigned int u0 = (__float_as_uint(d0) & 0xFFFFFC00u) | (unsigned)(j);
                unsigned int u1 = (__float_as_uint(d1) & 0xFFFFFC00u) | (unsigned)(j+1);
                unsigned int u2 = (__float_as_uint(d2) & 0xFFFFFC00u) | (unsigned)(j+2);
                unsigned int u3 = (__float_as_uint(d3) & 0xFFFFFC00u) | (unsigned)(j+3);
                mu[i] = min(min(mu[i], u0), min(min(u1, u2), u3));
            }
        }
        // prior stream
        for (int j = 0; j < NPRIOR; j += 4) {
            float4 t0 = s_p[j], t1 = s_p[j+1], t2 = s_p[j+2], t3 = s_p[j+3];
#pragma unroll
            for (int i = 0; i < PPT; ++i) {
                float d0 = fmaf(nax[i], t0.x, fmaf(nay[i], t0.y, fmaf(naz[i], t0.z, t0.w)));
                float d1 = fmaf(nax[i], t1.x, fmaf(nay[i], t1.y, fmaf(naz[i], t1.z, t1.w)));
                float d2 = fmaf(nax[i], t2.x, fmaf(nay[i], t2.y, fmaf(naz[i], t2.z, t2.w)));
                float d3 = fmaf(nax[i], t3.x, fmaf(nay[i], t3.y, fmaf(naz[i], t3.z, t3.w)));
                mpri[i] = fminf(fminf(mpri[i], d0), fminf(d2, fminf(d1, d3)));
            }
        }
        float lS_cmap = 0.0f, lN_cmap = 0.0f, lS_pen = 0.0f;
        float dr[PPT];
#pragma unroll
        for (int i = 0; i < PPT; ++i) {
            float dpri = fmaxf(a2[i] + (mpri[i] - BIAS), 0.0f);
            int j = (int)(mu[i] & 0x3FFu);
            float4 t  = s_t[j];
            float4 nr = nrm4v[j];
            float dot = fmaf(nax[i], t.x, fmaf(nay[i], t.y, fmaf(naz[i], t.z, t.w - BIAS)));
            float drec = fmaxf(a2[i] + dot, 0.0f);
            dr[i] = drec;
            bool cm = drec < 1e-4f;               // d_rec < 0.01^2
            if (cm) { lS_cmap += dpri; lN_cmap += 1.0f; }
            float ddot = (t.x - px[i]) * nr.x
                       + (t.y - py[i]) * nr.y
                       + (t.z - pz[i]) * nr.z;
            if (ddot > 0.0f) lS_pen += drec;
        }
        *(float4*)(drec_arr + (size_t)b * N1V + (size_t)chunk * 1024 + (size_t)tid * 4) =
            make_float4(dr[0], dr[1], dr[2], dr[3]);
        atomicAdd(&s_red[0], lS_cmap);
        atomicAdd(&s_red[1], lN_cmap);
        atomicAdd(&s_red[2], lS_pen);
        __syncthreads();
        if (tid < 8) {
            float v = 0.0f;
            if (tid == 3) v = s_red[0];
            if (tid == 4) v = s_red[1];
            if (tid == 7) v = s_red[2];
            part[(size_t)blk * 8 + tid] = v;
        }
        return;
    }

    if (blk < REC_BLOCKS + GT_BLOCKS) {
        // ============ GT ROLE ============
        int r = blk - REC_BLOCKS;
        int b = r >> 3, chunk = r & 7;
        const float4* gt4v = ws4 + (size_t)b * BATCH_F4;
        for (int j = tid; j < NVP; j += 256) s_t[j] = gt4v[j];
        if (tid == 0) s_red[0] = 0.0f;
        __syncthreads();

        const float* ob = obj + ((size_t)b * N1V + (size_t)chunk * 1024) * 3;
        const float4* ob4 = (const float4*)(ob + (size_t)tid * PPT * 3);
        float4 q0 = ob4[0], q1 = ob4[1], q2 = ob4[2];
        float px[PPT], py[PPT], pz[PPT];
        px[0]=q0.x; py[0]=q0.y; pz[0]=q0.z;
        px[1]=q0.w; py[1]=q1.x; pz[1]=q1.y;
        px[2]=q1.z; py[2]=q1.w; pz[2]=q2.x;
        px[3]=q2.y; py[3]=q2.z; pz[3]=q2.w;

        float nax[PPT], nay[PPT], naz[PPT], a2[PPT], mgt[PPT];
#pragma unroll
        for (int i = 0; i < PPT; ++i) {
            nax[i] = -2.0f * px[i]; nay[i] = -2.0f * py[i]; naz[i] = -2.0f * pz[i];
            a2[i] = px[i]*px[i] + py[i]*py[i] + pz[i]*pz[i];
            mgt[i] = 3.4e38f;
        }
        for (int j = 0; j < NVP; j += 4) {
            float4 t0 = s_t[j], t1 = s_t[j+1], t2 = s_t[j+2], t3 = s_t[j+3];
#pragma unroll
            for (int i = 0; i < PPT; ++i) {
                float d0 = fmaf(nax[i], t0.x, fmaf(nay[i], t0.y, fmaf(naz[i], t0.z, t0.w)));
                float d1 = fmaf(nax[i], t1.x, fmaf(nay[i], t1.y, fmaf(naz[i], t1.z, t1.w)));
                float d2 = fmaf(nax[i], t2.x, fmaf(nay[i], t2.y, fmaf(naz[i], t2.z, t2.w)));
                float d3 = fmaf(nax[i], t3.x, fmaf(nay[i], t3.y, fmaf(naz[i], t3.z, t3.w)));
                mgt[i] = fminf(fminf(mgt[i], d0), fminf(d2, fminf(d1, d3)));
            }
        }
        float lN_gt = 0.0f;
        unsigned int gbits = 0;
#pragma unroll
        for (int i = 0; i < PPT; ++i) {
            float dgt = fmaxf(a2[i] + mgt[i], 0.0f);
            bool gc = sqrtf(dgt) < 0.005f;
            if (gc) { lN_gt += 1.0f; gbits |= (1u << (8 * i)); }
        }
        gc_arr[(size_t)r * 256 + tid] = gbits;
        atomicAdd(&s_red[0], lN_gt);
        __syncthreads();
        if (tid < 8) {
            float v = (tid == 5) ? s_red[0] : 0.0f;
            part[(size_t)blk * 8 + tid] = v;
        }
        return;
    }

    // ============ CHAMFER ROLE ============
    {
        int c    = blk - (REC_BLOCKS + GT_BLOCKS);
        int b    = c >> 2;
        int dir  = (c >> 1) & 1;   // 0: rec->gt, 1: gt->rec
        int half = c & 1;
        const float4* base = ws4 + (size_t)b * BATCH_F4;
        const float4* srcv = dir ? base : (base + NVP);   // gt4 : rec4
        const float4* tgtv = dir ? (base + NVP) : base;   // rec4 : gt4
        for (int j = tid; j < NVP; j += 256) s_t[j] = tgtv[j];
        if (tid == 0) s_red[0] = 0.0f;
        __syncthreads();

        const int CPT = 2;               // 256*2 = 512 >= 389 sources
        float nax[CPT], nay[CPT], naz[CPT], a2[CPT], m[CPT];
        bool valid[CPT];
#pragma unroll
        for (int k = 0; k < CPT; ++k) {
            int p = half * HALF_SRC + tid + 256 * k;
            valid[k] = (p < (half + 1) * HALF_SRC);
            float4 s = srcv[valid[k] ? p : 0];
            nax[k] = -2.0f * s.x; nay[k] = -2.0f * s.y; naz[k] = -2.0f * s.z;
            a2[k] = s.w;                  // one of src/tgt carries +BIAS
            m[k] = 3.4e38f;
        }
        for (int j = 0; j < NVP; j += 4) {
            float4 t0 = s_t[j], t1 = s_t[j+1], t2 = s_t[j+2], t3 = s_t[j+3];
#pragma unroll
            for (int k = 0; k < CPT; ++k) {
                float d0 = fmaf(nax[k], t0.x, fmaf(nay[k], t0.y, fmaf(naz[k], t0.z, t0.w)));
                float d1 = fmaf(nax[k], t1.x, fmaf(nay[k], t1.y, fmaf(naz[k], t1.z, t1.w)));
                float d2 = fmaf(nax[k], t2.x, fmaf(nay[k], t2.y, fmaf(naz[k], t2.z, t2.w)));
                float d3 = fmaf(nax[k], t3.x, fmaf(nay[k], t3.y, fmaf(naz[k], t3.z, t3.w)));
                m[k] = fminf(fminf(m[k], d0), fminf(d2, fminf(d1, d3)));
            }
        }
        float local = 0.0f;
#pragma unroll
        for (int k = 0; k < CPT; ++k)
            if (valid[k]) local += fmaxf(a2[k] + m[k] - BIAS, 0.0f);
        atomicAdd(&s_red[0], local);
        __syncthreads();
        if (tid < 8) {
            float v = (tid == 2) ? s_red[0] : 0.0f;
            part[(size_t)blk * 8 + tid] = v;
        }
    }
}

// ---------------- Combine: consistency count = sum(rc & gc) ----------------
__global__ __launch_bounds__(256) void k_combine(const float* __restrict__ drec_arr,
                                                 const unsigned int* __restrict__ gc_arr,
                                                 float* __restrict__ part) {
    int blk = blockIdx.x, tid = threadIdx.x;
    __shared__ float s_red;
    if (tid == 0) s_red = 0.0f;
    __syncthreads();
    float4 d4 = *(const float4*)(drec_arr + (size_t)blk * 1024 + (size_t)tid * 4);
    unsigned int g4 = gc_arr[(size_t)blk * 256 + tid];
    float cnt = 0.0f;
    if ((sqrtf(d4.x) < 0.005f) && (g4 & 0x000000FFu)) cnt += 1.0f;
    if ((sqrtf(d4.y) < 0.005f) && (g4 & 0x0000FF00u)) cnt += 1.0f;
    if ((sqrtf(d4.z) < 0.005f) && (g4 & 0x00FF0000u)) cnt += 1.0f;
    if ((sqrtf(d4.w) < 0.005f) && (g4 & 0xFF000000u)) cnt += 1.0f;
    atomicAdd(&s_red, cnt);
    __syncthreads();
    if (tid < 8) {
        float v = (tid == 6) ? s_red : 0.0f;
        part[(size_t)(NROLE_BLOCKS + blk) * 8 + tid] = v;
    }
}

// ---------------- Finalize: param/KLD reductions + partial row-sum + loss ----
__global__ __launch_bounds__(256) void k_final(const float* __restrict__ part,
                                               const float* __restrict__ mean,
                                               const float* __restrict__ log_var,
                                               const float* __restrict__ rp,
                                               const float* __restrict__ xp,
                                               float* __restrict__ out) {
    int tid = threadIdx.x;
    __shared__ float red[8];
    if (tid < 8) red[tid] = 0.0f;
    __syncthreads();
    float l2=0, l3=0, l4=0, l5=0, l6=0, l7=0;
    for (int r = tid; r < TOT_ROWS; r += 256) {
        const float* row = part + (size_t)r * 8;
        l2 += row[2]; l3 += row[3]; l4 += row[4];
        l5 += row[5]; l6 += row[6]; l7 += row[7];
    }
    float s_param = 0.0f, s_kld = 0.0f;
    for (int i = tid; i < NB * NPAR; i += 256) {
        float d = rp[i] - xp[i];
        s_param += d * d;
    }
    for (int i = tid; i < NB * NZ; i += 256) {
        float m = mean[i], lv = log_var[i];
        s_kld += 1.0f + lv - m * m - expf(lv);
    }
    atomicAdd(&red[0], s_param);
    atomicAdd(&red[1], s_kld);
    atomicAdd(&red[2], l2);
    atomicAdd(&red[3], l3);
    atomicAdd(&red[4], l4);
    atomicAdd(&red[5], l5);
    atomicAdd(&red[6], l6);
    atomicAdd(&red[7], l7);
    __syncthreads();
    if (tid == 0) {
        const float fB = 64.0f;
        float param_loss  = red[0] / fB;
        float KLD         = -0.5f * red[1] / fB * 10.0f;
        float recon_loss  = red[2] / fB;
        float cmap_loss   = 3000.0f * red[3] / (fB * red[4]);
        float consistency = -5.0f * red[6] / (red[5] + 0.0001f);
        float penetr      = 100.0f * red[7] / fB;
        out[0] = (recon_loss + KLD) + 0.1f * param_loss + 1000.0f * cmap_loss
               + 10.0f * consistency + 10.0f * penetr;
    }
}

extern "C" void kernel_launch(void* const* d_in, const int* in_sizes, int n_in,
                              void* d_out, int out_size, void* d_ws, size_t ws_size,
                              hipStream_t stream) {
    (void)in_sizes; (void)n_in; (void)out_size; (void)ws_size;
    const float* obj     = (const float*)d_in[0];
    const float* recon   = (const float*)d_in[1];
    const float* gt      = (const float*)d_in[2];
    const float* mean    = (const float*)d_in[3];
    const float* log_var = (const float*)d_in[4];
    const float* rp      = (const float*)d_in[5];
    const float* xp      = (const float*)d_in[6];
    const int*   faces   = (const int*)d_in[7];
    float4* ws4 = (float4*)d_ws;
    float* part = (float*)d_ws + PART_OFF;
    float* drec = (float*)d_ws + DREC_OFF;
    unsigned int* gc = (unsigned int*)((float*)d_ws + GC_OFF);
    float* out  = (float*)d_out;

    k_prep   <<<NB,           256, 0, stream>>>(recon, gt, faces, ws4);
    k_fused  <<<NROLE_BLOCKS, 256, 0, stream>>>(obj, ws4, part, drec, gc);
    k_combine<<<CMB_BLOCKS,   256, 0, stream>>>(drec, gc, part);
    k_final  <<<1,            256, 0, stream>>>(part, mean, log_var, rp, xp, out);
}

// Round 7
// 208.374 us; speedup vs baseline: 1.5886x; 1.0201x over previous
//
#include <hip/hip_runtime.h>
#include <math.h>

// Problem constants (from reference setup_inputs)
#define NB     64      // batch
#define N1V    8192    // obj points per batch
#define NV     778     // recon / gt verts
#define NVP    780     // padded to multiple of 4
#define NFACE  1538
#define NZ     64
#define NPAR   61
#define NPRIOR 204
#define PPT    8       // obj points per thread (rec/gt roles)
#define BIAS   0.0625f // makes rec/pri partial distance non-negative (2ab <= 0.06)

// role block ranges in k_fused
#define REC_BLOCKS 256                       // (batch, chunk-of-2048): rec + prior
#define GT_BLOCKS  256                       // (batch, chunk-of-2048): gt
#define CH_BLOCKS  128                       // (batch, dir): chamfer, 8 src/thread
#define NROLE_BLOCKS (REC_BLOCKS + GT_BLOCKS + CH_BLOCKS)   // 640
#define CMB_BLOCKS 256
#define TOT_ROWS   (NROLE_BLOCKS + CMB_BLOCKS)              // 896

// ws float4 layout per batch (BATCH_F4 float4s):
//   [0,780)     gt4   (x,y,z,|t|^2), pads w=1e30
//   [780,1560)  rec4  (x,y,z,|t|^2+BIAS), pads w=1e30
//   [1560,1764) pri4  (biased, subset of rec4)
//   [1764,2542) nrm4  (nx,ny,nz,0)
#define BATCH_F4 2544
// float offsets in ws
#define PART_OFF (NB * BATCH_F4 * 4)          // partials[TOT_ROWS][8]
#define DREC_OFF (PART_OFF + TOT_ROWS * 8)    // drec[NB*N1V]
#define GC_OFF   (DREC_OFF + NB * N1V)        // gc bitmasks, 1 uint / 8 points

__device__ __constant__ int c_prior[NPRIOR] = {
  697,698,699,700,712,713,714,715,737,738,739,740,741,743,744,745,746,748,749,750,
  753,754,755,756,757,758,759,760,761,762,763,764,765,766,767,768,
  46,47,48,49,164,165,166,167,194,195,223,237,238,280,281,298,301,317,320,323,
  324,325,326,327,328,329,330,331,332,333,340,341,342,343,344,345,346,347,348,349,
  350,351,352,353,354,355,
  356,357,358,359,375,376,386,387,396,397,402,403,413,429,433,434,435,436,437,438,
  439,440,441,442,443,444,452,453,454,455,456,459,460,461,462,463,464,465,466,467,
  468,469,470,471,484,485,486,496,497,506,507,513,514,524,545,546,547,548,549,550,
  551,552,553,555,563,564,565,566,567,570,572,573,574,575,576,577,578,
  580,581,582,583,600,601,602,614,615,624,625,630,631,641,663,664,665,666,667,668,
  670,672,680,681,682,683,684,686,687,688,689,690,691,692,693,694,695,
  73,96,98,99,772,774,775,777
};

// ---------------- Kernel 0: per-batch target arrays + normals ----------------
__global__ __launch_bounds__(256) void k_prep(const float* __restrict__ recon,
                                              const float* __restrict__ gt,
                                              const int* __restrict__ faces,
                                              float4* __restrict__ ws4) {
    int b = blockIdx.x, tid = threadIdx.x;
    __shared__ float4 s_r[NV];
    __shared__ float s_vnx[NV], s_vny[NV], s_vnz[NV];
    const float* rb = recon + (size_t)b * NV * 3;
    const float* gb = gt    + (size_t)b * NV * 3;
    float4* gt4  = ws4 + (size_t)b * BATCH_F4;
    float4* rec4 = gt4 + NVP;
    float4* pri4 = rec4 + NVP;
    float4* nrm4 = pri4 + NPRIOR;
    for (int j = tid; j < NVP; j += 256) {
        if (j < NV) {
            float x = rb[3*j], y = rb[3*j+1], z = rb[3*j+2];
            float4 r = make_float4(x, y, z, x*x + y*y + z*z + BIAS);
            s_r[j] = r; rec4[j] = r;
            x = gb[3*j]; y = gb[3*j+1]; z = gb[3*j+2];
            gt4[j] = make_float4(x, y, z, x*x + y*y + z*z);
            s_vnx[j] = 0.0f; s_vny[j] = 0.0f; s_vnz[j] = 0.0f;
        } else {
            float4 pad = make_float4(0.f, 0.f, 0.f, 1e30f);
            rec4[j] = pad; gt4[j] = pad;
        }
    }
    __syncthreads();
    for (int f = tid; f < NFACE; f += 256) {
        int i0 = faces[3*f], i1 = faces[3*f+1], i2 = faces[3*f+2];
        float4 p0 = s_r[i0], p1 = s_r[i1], p2 = s_r[i2];
        float e1x = p1.x - p0.x, e1y = p1.y - p0.y, e1z = p1.z - p0.z;
        float e2x = p2.x - p0.x, e2y = p2.y - p0.y, e2z = p2.z - p0.z;
        float fx = e1y * e2z - e1z * e2y;
        float fy = e1z * e2x - e1x * e2z;
        float fz = e1x * e2y - e1y * e2x;
        atomicAdd(&s_vnx[i0], fx); atomicAdd(&s_vny[i0], fy); atomicAdd(&s_vnz[i0], fz);
        atomicAdd(&s_vnx[i1], fx); atomicAdd(&s_vny[i1], fy); atomicAdd(&s_vnz[i1], fz);
        atomicAdd(&s_vnx[i2], fx); atomicAdd(&s_vny[i2], fy); atomicAdd(&s_vnz[i2], fz);
    }
    __syncthreads();
    for (int j = tid; j < NV; j += 256) {
        float x = s_vnx[j], y = s_vny[j], z = s_vnz[j];
        float inv = 1.0f / (sqrtf(x*x + y*y + z*z) + 1e-12f);
        nrm4[j] = make_float4(x * inv, y * inv, z * inv, 0.0f);
    }
    for (int k = tid; k < NPRIOR; k += 256) pri4[k] = s_r[c_prior[k]];
}

// ---------------- Fused role kernel ----------------
// blocks [0,256): rec+prior KNN  [256,512): gt KNN  [512,640): chamfer
__global__ __launch_bounds__(256) void k_fused(const float* __restrict__ obj,
                                               const float4* __restrict__ ws4,
                                               float* __restrict__ part,
                                               float* __restrict__ drec_arr,
                                               unsigned int* __restrict__ gc_arr) {
    __shared__ float4 s_t[NVP];
    __shared__ float4 s_p[NPRIOR];
    __shared__ float s_red[4];
    int tid = threadIdx.x;
    int blk = blockIdx.x;

    if (blk < REC_BLOCKS) {
        // ============ REC + PRIOR ROLE (PPT=8) ============
        int b = blk >> 2, chunk = blk & 3;
        const float4* base = ws4 + (size_t)b * BATCH_F4;
        const float4* rec4v = base + NVP;
        const float4* pri4v = base + 2 * NVP;
        const float4* nrm4v = pri4v + NPRIOR;
        for (int j = tid; j < NVP; j += 256) s_t[j] = rec4v[j];
        for (int k = tid; k < NPRIOR; k += 256) s_p[k] = pri4v[k];
        if (tid < 4) s_red[tid] = 0.0f;
        __syncthreads();

        const float* ob = obj + ((size_t)b * N1V + (size_t)chunk * 2048) * 3;
        const float4* ob4 = (const float4*)(ob + (size_t)tid * 24);
        float4 q0 = ob4[0], q1 = ob4[1], q2 = ob4[2], q3 = ob4[3], q4 = ob4[4], q5 = ob4[5];

        float nax[PPT], nay[PPT], naz[PPT], a2[PPT], mpri[PPT];
        unsigned int mu[PPT];
        {
            float px[PPT], py[PPT], pz[PPT];
            px[0]=q0.x; py[0]=q0.y; pz[0]=q0.z;
            px[1]=q0.w; py[1]=q1.x; pz[1]=q1.y;
            px[2]=q1.z; py[2]=q1.w; pz[2]=q2.x;
            px[3]=q2.y; py[3]=q2.z; pz[3]=q2.w;
            px[4]=q3.x; py[4]=q3.y; pz[4]=q3.z;
            px[5]=q3.w; py[5]=q4.x; pz[5]=q4.y;
            px[6]=q4.z; py[6]=q4.w; pz[6]=q5.x;
            px[7]=q5.y; py[7]=q5.z; pz[7]=q5.w;
#pragma unroll
            for (int i = 0; i < PPT; ++i) {
                nax[i] = -2.0f * px[i]; nay[i] = -2.0f * py[i]; naz[i] = -2.0f * pz[i];
                a2[i] = px[i]*px[i] + py[i]*py[i] + pz[i]*pz[i];
                mpri[i] = 3.4e38f; mu[i] = 0xFFFFFFFFu;
            }
        }
        // rec stream: packed (distance|index) uint-min argmin (biased d >= 0)
        for (int j = 0; j < NVP; j += 4) {
            float4 t0 = s_t[j], t1 = s_t[j+1], t2 = s_t[j+2], t3 = s_t[j+3];
#pragma unroll
            for (int i = 0; i < PPT; ++i) {
                float d0 = fmaf(nax[i], t0.x, fmaf(nay[i], t0.y, fmaf(naz[i], t0.z, t0.w)));
                float d1 = fmaf(nax[i], t1.x, fmaf(nay[i], t1.y, fmaf(naz[i], t1.z, t1.w)));
                float d2 = fmaf(nax[i], t2.x, fmaf(nay[i], t2.y, fmaf(naz[i], t2.z, t2.w)));
                float d3 = fmaf(nax[i], t3.x, fmaf(nay[i], t3.y, fmaf(naz[i], t3.z, t3.w)));
                unsigned int u0 = (__float_as_uint(d0) & 0xFFFFFC00u) | (unsigned)(j);
                unsigned int u1 = (__float_as_uint(d1) & 0xFFFFFC00u) | (unsigned)(j+1);
                unsigned int u2 = (__float_as_uint(d2) & 0xFFFFFC00u) | (unsigned)(j+2);
                unsigned int u3 = (__float_as_uint(d3) & 0xFFFFFC00u) | (unsigned)(j+3);
                mu[i] = min(min(mu[i], u0), min(min(u1, u2), u3));
            }
        }
        // prior stream
        for (int j = 0; j < NPRIOR; j += 4) {
            float4 t0 = s_p[j], t1 = s_p[j+1], t2 = s_p[j+2], t3 = s_p[j+3];
#pragma unroll
            for (int i = 0; i < PPT; ++i) {
                float d0 = fmaf(nax[i], t0.x, fmaf(nay[i], t0.y, fmaf(naz[i], t0.z, t0.w)));
                float d1 = fmaf(nax[i], t1.x, fmaf(nay[i], t1.y, fmaf(naz[i], t1.z, t1.w)));
                float d2 = fmaf(nax[i], t2.x, fmaf(nay[i], t2.y, fmaf(naz[i], t2.z, t2.w)));
                float d3 = fmaf(nax[i], t3.x, fmaf(nay[i], t3.y, fmaf(naz[i], t3.z, t3.w)));
                mpri[i] = fminf(fminf(mpri[i], d0), fminf(d2, fminf(d1, d3)));
            }
        }
        float lS_cmap = 0.0f, lN_cmap = 0.0f, lS_pen = 0.0f;
        float dr[PPT];
#pragma unroll
        for (int i = 0; i < PPT; ++i) {
            float dpri = fmaxf(a2[i] + (mpri[i] - BIAS), 0.0f);
            int j = (int)(mu[i] & 0x3FFu);
            float4 t  = s_t[j];
            float4 nr = nrm4v[j];
            float dot = fmaf(nax[i], t.x, fmaf(nay[i], t.y, fmaf(naz[i], t.z, t.w - BIAS)));
            float drec = fmaxf(a2[i] + dot, 0.0f);
            dr[i] = drec;
            bool cm = drec < 1e-4f;               // d_rec < 0.01^2
            if (cm) { lS_cmap += dpri; lN_cmap += 1.0f; }
            float ddot = (t.x + 0.5f * nax[i]) * nr.x
                       + (t.y + 0.5f * nay[i]) * nr.y
                       + (t.z + 0.5f * naz[i]) * nr.z;
            if (ddot > 0.0f) lS_pen += drec;
        }
        float* dbase = drec_arr + (size_t)b * N1V + (size_t)chunk * 2048 + (size_t)tid * 8;
        *(float4*)dbase       = make_float4(dr[0], dr[1], dr[2], dr[3]);
        *(float4*)(dbase + 4) = make_float4(dr[4], dr[5], dr[6], dr[7]);
        atomicAdd(&s_red[0], lS_cmap);
        atomicAdd(&s_red[1], lN_cmap);
        atomicAdd(&s_red[2], lS_pen);
        __syncthreads();
        if (tid < 8) {
            float v = 0.0f;
            if (tid == 3) v = s_red[0];
            if (tid == 4) v = s_red[1];
            if (tid == 7) v = s_red[2];
            part[(size_t)blk * 8 + tid] = v;
        }
        return;
    }

    if (blk < REC_BLOCKS + GT_BLOCKS) {
        // ============ GT ROLE (PPT=8) ============
        int r = blk - REC_BLOCKS;
        int b = r >> 2, chunk = r & 3;
        const float4* gt4v = ws4 + (size_t)b * BATCH_F4;
        for (int j = tid; j < NVP; j += 256) s_t[j] = gt4v[j];
        if (tid == 0) s_red[0] = 0.0f;
        __syncthreads();

        const float* ob = obj + ((size_t)b * N1V + (size_t)chunk * 2048) * 3;
        const float4* ob4 = (const float4*)(ob + (size_t)tid * 24);
        float4 q0 = ob4[0], q1 = ob4[1], q2 = ob4[2], q3 = ob4[3], q4 = ob4[4], q5 = ob4[5];

        float nax[PPT], nay[PPT], naz[PPT], a2[PPT], mgt[PPT];
        {
            float px[PPT], py[PPT], pz[PPT];
            px[0]=q0.x; py[0]=q0.y; pz[0]=q0.z;
            px[1]=q0.w; py[1]=q1.x; pz[1]=q1.y;
            px[2]=q1.z; py[2]=q1.w; pz[2]=q2.x;
            px[3]=q2.y; py[3]=q2.z; pz[3]=q2.w;
            px[4]=q3.x; py[4]=q3.y; pz[4]=q3.z;
            px[5]=q3.w; py[5]=q4.x; pz[5]=q4.y;
            px[6]=q4.z; py[6]=q4.w; pz[6]=q5.x;
            px[7]=q5.y; py[7]=q5.z; pz[7]=q5.w;
#pragma unroll
            for (int i = 0; i < PPT; ++i) {
                nax[i] = -2.0f * px[i]; nay[i] = -2.0f * py[i]; naz[i] = -2.0f * pz[i];
                a2[i] = px[i]*px[i] + py[i]*py[i] + pz[i]*pz[i];
                mgt[i] = 3.4e38f;
            }
        }
        for (int j = 0; j < NVP; j += 4) {
            float4 t0 = s_t[j], t1 = s_t[j+1], t2 = s_t[j+2], t3 = s_t[j+3];
#pragma unroll
            for (int i = 0; i < PPT; ++i) {
                float d0 = fmaf(nax[i], t0.x, fmaf(nay[i], t0.y, fmaf(naz[i], t0.z, t0.w)));
                float d1 = fmaf(nax[i], t1.x, fmaf(nay[i], t1.y, fmaf(naz[i], t1.z, t1.w)));
                float d2 = fmaf(nax[i], t2.x, fmaf(nay[i], t2.y, fmaf(naz[i], t2.z, t2.w)));
                float d3 = fmaf(nax[i], t3.x, fmaf(nay[i], t3.y, fmaf(naz[i], t3.z, t3.w)));
                mgt[i] = fminf(fminf(mgt[i], d0), d1);
                mgt[i] = fminf(fminf(mgt[i], d2), d3);
            }
        }
        float lN_gt = 0.0f;
        unsigned int gbits = 0;
#pragma unroll
        for (int i = 0; i < PPT; ++i) {
            float dgt = fmaxf(a2[i] + mgt[i], 0.0f);
            bool gc = sqrtf(dgt) < 0.005f;
            if (gc) { lN_gt += 1.0f; gbits |= (1u << i); }
        }
        gc_arr[(size_t)r * 256 + tid] = gbits;
        atomicAdd(&s_red[0], lN_gt);
        __syncthreads();
        if (tid < 8) {
            float v = (tid == 5) ? s_red[0] : 0.0f;
            part[(size_t)blk * 8 + tid] = v;
        }
        return;
    }

    // ============ CHAMFER ROLE (8 sources/thread) ============
    {
        int c   = blk - (REC_BLOCKS + GT_BLOCKS);
        int b   = c >> 1;
        int dir = c & 1;           // 0: rec->gt, 1: gt->rec
        const float4* base = ws4 + (size_t)b * BATCH_F4;
        const float4* srcv = dir ? base : (base + NVP);   // gt4 : rec4
        const float4* tgtv = dir ? (base + NVP) : base;   // rec4 : gt4
        for (int j = tid; j < NVP; j += 256) s_t[j] = tgtv[j];
        if (tid == 0) s_red[0] = 0.0f;
        __syncthreads();

        const int CPT = 4;               // 256*4 = 1024 >= 778 sources
        float nax[CPT], nay[CPT], naz[CPT], a2[CPT], m[CPT];
        bool valid[CPT];
#pragma unroll
        for (int k = 0; k < CPT; ++k) {
            int p = tid + 256 * k;
            valid[k] = (p < NV);
            float4 s = srcv[valid[k] ? p : 0];
            nax[k] = -2.0f * s.x; nay[k] = -2.0f * s.y; naz[k] = -2.0f * s.z;
            a2[k] = s.w;                  // one of src/tgt carries +BIAS
            m[k] = 3.4e38f;
        }
        for (int j = 0; j < NVP; j += 4) {
            float4 t0 = s_t[j], t1 = s_t[j+1], t2 = s_t[j+2], t3 = s_t[j+3];
#pragma unroll
            for (int k = 0; k < CPT; ++k) {
                float d0 = fmaf(nax[k], t0.x, fmaf(nay[k], t0.y, fmaf(naz[k], t0.z, t0.w)));
                float d1 = fmaf(nax[k], t1.x, fmaf(nay[k], t1.y, fmaf(naz[k], t1.z, t1.w)));
                float d2 = fmaf(nax[k], t2.x, fmaf(nay[k], t2.y, fmaf(naz[k], t2.z, t2.w)));
                float d3 = fmaf(nax[k], t3.x, fmaf(nay[k], t3.y, fmaf(naz[k], t3.z, t3.w)));
                m[k] = fminf(fminf(m[k], d0), d1);
                m[k] = fminf(fminf(m[k], d2), d3);
            }
        }
        float local = 0.0f;
#pragma unroll
        for (int k = 0; k < CPT; ++k)
            if (valid[k]) local += fmaxf(a2[k] + m[k] - BIAS, 0.0f);
        atomicAdd(&s_red[0], local);
        __syncthreads();
        if (tid < 8) {
            float v = (tid == 2) ? s_red[0] : 0.0f;
            part[(size_t)blk * 8 + tid] = v;
        }
    }
}

// ---------------- Combine: consistency count = sum(rc & gc) ----------------
__global__ __launch_bounds__(256) void k_combine(const float* __restrict__ drec_arr,
                                                 const unsigned int* __restrict__ gc_arr,
                                                 float* __restrict__ part) {
    int blk = blockIdx.x, tid = threadIdx.x;
    __shared__ float s_red;
    if (tid == 0) s_red = 0.0f;
    __syncthreads();
    const float* dbase = drec_arr + (size_t)blk * 2048 + (size_t)tid * 8;
    float4 da = *(const float4*)dbase;
    float4 db = *(const float4*)(dbase + 4);
    unsigned int g = gc_arr[(size_t)blk * 256 + tid];
    float cnt = 0.0f;
    if ((sqrtf(da.x) < 0.005f) && (g & 0x01u)) cnt += 1.0f;
    if ((sqrtf(da.y) < 0.005f) && (g & 0x02u)) cnt += 1.0f;
    if ((sqrtf(da.z) < 0.005f) && (g & 0x04u)) cnt += 1.0f;
    if ((sqrtf(da.w) < 0.005f) && (g & 0x08u)) cnt += 1.0f;
    if ((sqrtf(db.x) < 0.005f) && (g & 0x10u)) cnt += 1.0f;
    if ((sqrtf(db.y) < 0.005f) && (g & 0x20u)) cnt += 1.0f;
    if ((sqrtf(db.z) < 0.005f) && (g & 0x40u)) cnt += 1.0f;
    if ((sqrtf(db.w) < 0.005f) && (g & 0x80u)) cnt += 1.0f;
    atomicAdd(&s_red, cnt);
    __syncthreads();
    if (tid < 8) {
        float v = (tid == 6) ? s_red : 0.0f;
        part[(size_t)(NROLE_BLOCKS + blk) * 8 + tid] = v;
    }
}

// ---------------- Finalize: param/KLD reductions + partial row-sum + loss ----
__global__ __launch_bounds__(256) void k_final(const float* __restrict__ part,
                                               const float* __restrict__ mean,
                                               const float* __restrict__ log_var,
                                               const float* __restrict__ rp,
                                               const float* __restrict__ xp,
                                               float* __restrict__ out) {
    int tid = threadIdx.x;
    __shared__ float red[8];
    if (tid < 8) red[tid] = 0.0f;
    __syncthreads();
    float l2=0, l3=0, l4=0, l5=0, l6=0, l7=0;
    for (int r = tid; r < TOT_ROWS; r += 256) {
        const float* row = part + (size_t)r * 8;
        l2 += row[2]; l3 += row[3]; l4 += row[4];
        l5 += row[5]; l6 += row[6]; l7 += row[7];
    }
    float s_param = 0.0f, s_kld = 0.0f;
    for (int i = tid; i < NB * NPAR; i += 256) {
        float d = rp[i] - xp[i];
        s_param += d * d;
    }
    for (int i = tid; i < NB * NZ; i += 256) {
        float m = mean[i], lv = log_var[i];
        s_kld += 1.0f + lv - m * m - expf(lv);
    }
    atomicAdd(&red[0], s_param);
    atomicAdd(&red[1], s_kld);
    atomicAdd(&red[2], l2);
    atomicAdd(&red[3], l3);
    atomicAdd(&red[4], l4);
    atomicAdd(&red[5], l5);
    atomicAdd(&red[6], l6);
    atomicAdd(&red[7], l7);
    __syncthreads();
    if (tid == 0) {
        const float fB = 64.0f;
        float param_loss  = red[0] / fB;
        float KLD         = -0.5f * red[1] / fB * 10.0f;
        float recon_loss  = red[2] / fB;
        float cmap_loss   = 3000.0f * red[3] / (fB * red[4]);
        float consistency = -5.0f * red[6] / (red[5] + 0.0001f);
        float penetr      = 100.0f * red[7] / fB;
        out[0] = (recon_loss + KLD) + 0.1f * param_loss + 1000.0f * cmap_loss
               + 10.0f * consistency + 10.0f * penetr;
    }
}

extern "C" void kernel_launch(void* const* d_in, const int* in_sizes, int n_in,
                              void* d_out, int out_size, void* d_ws, size_t ws_size,
                              hipStream_t stream) {
    (void)in_sizes; (void)n_in; (void)out_size; (void)ws_size;
    const float* obj     = (const float*)d_in[0];
    const float* recon   = (const float*)d_in[1];
    const float* gt      = (const float*)d_in[2];
    const float* mean    = (const float*)d_in[3];
    const float* log_var = (const float*)d_in[4];
    const float* rp      = (const float*)d_in[5];
    const float* xp      = (const float*)d_in[6];
    const int*   faces   = (const int*)d_in[7];
    float4* ws4 = (float4*)d_ws;
    float* part = (float*)d_ws + PART_OFF;
    float* drec = (float*)d_ws + DREC_OFF;
    unsigned int* gc = (unsigned int*)((float*)d_ws + GC_OFF);
    float* out  = (float*)d_out;

    k_prep   <<<NB,           256, 0, stream>>>(recon, gt, faces, ws4);
    k_fused  <<<NROLE_BLOCKS, 256, 0, stream>>>(obj, ws4, part, drec, gc);
    k_combine<<<CMB_BLOCKS,   256, 0, stream>>>(drec, gc, part);
    k_final  <<<1,            256, 0, stream>>>(part, mean, log_var, rp, xp, out);
}